// Round 1
// baseline (10818.561 us; speedup 1.0000x reference)
//
#include <hip/hip_runtime.h>

#define NEG_SLOPE 0.1f
__device__ __forceinline__ float lrelu(float v) { return v >= 0.f ? v : NEG_SLOPE * v; }

// ---------------------------------------------------------------------------
// Encoder: per node, conv1d(3->9,k3,s2) + lrelu, conv1d(9->1,k3,s2) + lrelu,
// concat with pose -> x[N][40].  One block (64 threads) per node.
// ---------------------------------------------------------------------------
__global__ void encoder_kernel(const float* __restrict__ pose,
                               const float* __restrict__ views,
                               const float* __restrict__ w1, const float* __restrict__ b1,
                               const float* __restrict__ w2, const float* __restrict__ b2,
                               float* __restrict__ x)
{
    __shared__ float s_in[3 * 151];   // 453
    __shared__ float s_c1[9 * 75];    // 675
    __shared__ float s_w1[81];
    __shared__ float s_b1[9];
    __shared__ float s_w2[27];
    __shared__ float s_b2;

    const int n = blockIdx.x;
    const int t = threadIdx.x;

    for (int i = t; i < 453; i += 64) s_in[i] = views[n * 453 + i];
    for (int i = t; i < 81; i += 64)  s_w1[i] = w1[i];
    if (t < 9)  s_b1[t] = b1[t];
    if (t < 27) s_w2[t] = w2[t];
    if (t == 0) s_b2 = b2[0];
    __syncthreads();

    // conv1: 9 out-channels x 75 positions
    for (int i = t; i < 675; i += 64) {
        const int oc = i / 75, ow = i % 75;
        float v = s_b1[oc];
        #pragma unroll
        for (int ic = 0; ic < 3; ic++) {
            #pragma unroll
            for (int k = 0; k < 3; k++)
                v += s_in[ic * 151 + 2 * ow + k] * s_w1[oc * 9 + ic * 3 + k];
        }
        s_c1[i] = lrelu(v);
    }
    __syncthreads();

    if (t < 3) {
        x[n * 40 + t] = pose[n * 3 + t];
    } else if (t < 40) {
        const int ow = t - 3;
        float v = s_b2;
        #pragma unroll
        for (int ic = 0; ic < 9; ic++) {
            #pragma unroll
            for (int k = 0; k < 3; k++)
                v += s_c1[ic * 75 + 2 * ow + k] * s_w2[ic * 3 + k];
        }
        x[n * 40 + t] = lrelu(v);
    }
}

// ---------------------------------------------------------------------------
// Scatter-add: agg[dst] += x[src] over all edges.  One thread per edge.
// ---------------------------------------------------------------------------
__global__ void scatter_kernel(const int* __restrict__ ei,
                               const float* __restrict__ x,
                               float* __restrict__ agg, int E)
{
    const int e = blockIdx.x * blockDim.x + threadIdx.x;
    if (e >= E) return;
    const int s = ei[e];
    const int d = ei[E + e];
    const float4* xs = (const float4*)(x + s * 40);
    float* ad = agg + d * 40;
    #pragma unroll
    for (int j = 0; j < 10; j++) {
        const float4 v = xs[j];
        atomicAdd(ad + 4 * j + 0, v.x);
        atomicAdd(ad + 4 * j + 1, v.y);
        atomicAdd(ad + 4 * j + 2, v.z);
        atomicAdd(ad + 4 * j + 3, v.w);
    }
}

// ---------------------------------------------------------------------------
// GraphConv: h[n][m] = lrelu( sum_k40 agg[n][k]*w_rel[m][k]
//                           + sum_k40 x[n][k]*w_root[m][k] + b_rel[m] )
// Treated as a K=80 GEMM with A = [agg | x], W = [w_rel | w_root].
// Block 256 threads computes a 64(node) x 64(m) tile; 4x4 per thread.
// LDS tiles stored transposed [k][n]/[k][m], padded to 68 for 16B alignment.
// ---------------------------------------------------------------------------
__global__ void graphconv_kernel(const float* __restrict__ agg,
                                 const float* __restrict__ x,
                                 const float* __restrict__ w_rel,
                                 const float* __restrict__ w_root,
                                 const float* __restrict__ b_rel,
                                 float* __restrict__ h, int N)
{
    __shared__ float s_A[80][68];
    __shared__ float s_W[80][68];

    const int t = threadIdx.x;
    const int n0 = blockIdx.x * 64;
    const int m0 = blockIdx.y * 64;

    for (int idx = t; idx < 64 * 40; idx += 256) {
        const int r = idx / 40, c = idx % 40;   // node r, k c
        const int n = n0 + r;
        s_A[c][r]      = (n < N) ? agg[n * 40 + c] : 0.f;
        s_A[c + 40][r] = (n < N) ? x[n * 40 + c]   : 0.f;
    }
    for (int idx = t; idx < 64 * 40; idx += 256) {
        const int r = idx / 40, c = idx % 40;   // m r, k c
        s_W[c][r]      = w_rel[(m0 + r) * 40 + c];
        s_W[c + 40][r] = w_root[(m0 + r) * 40 + c];
    }
    __syncthreads();

    const int tm = t % 16, tn = t / 16;
    float acc[4][4] = {};
    for (int k = 0; k < 80; k++) {
        const float4 a = *(const float4*)&s_A[k][tn * 4];
        const float4 w = *(const float4*)&s_W[k][tm * 4];
        const float av[4] = {a.x, a.y, a.z, a.w};
        const float wv[4] = {w.x, w.y, w.z, w.w};
        #pragma unroll
        for (int i = 0; i < 4; i++)
            #pragma unroll
            for (int j = 0; j < 4; j++)
                acc[i][j] += av[i] * wv[j];
    }

    #pragma unroll
    for (int i = 0; i < 4; i++) {
        const int n = n0 + tn * 4 + i;
        if (n >= N) continue;
        #pragma unroll
        for (int j = 0; j < 4; j++) {
            const int m = m0 + tm * 4 + j;
            h[n * 256 + m] = lrelu(acc[i][j] + b_rel[m]);
        }
    }
}

// ---------------------------------------------------------------------------
// MLP layer: C = lrelu(A @ W^T + b), A [N,256], W [256,256] (out-major).
// Same 64x64 tile / 4x4-per-thread structure, K chunked by 64.
// ---------------------------------------------------------------------------
__global__ void mlp_kernel(const float* __restrict__ A,
                           const float* __restrict__ W,
                           const float* __restrict__ b,
                           float* __restrict__ C, int N)
{
    __shared__ float s_A[64][68];
    __shared__ float s_W[64][68];

    const int t = threadIdx.x;
    const int n0 = blockIdx.x * 64;
    const int m0 = blockIdx.y * 64;
    const int tm = t % 16, tn = t / 16;

    float acc[4][4] = {};
    for (int kc = 0; kc < 256; kc += 64) {
        __syncthreads();
        for (int idx = t; idx < 64 * 64; idx += 256) {
            const int r = idx / 64, c = idx % 64;
            const int n = n0 + r;
            s_A[c][r] = (n < N) ? A[n * 256 + kc + c] : 0.f;
            s_W[c][r] = W[(m0 + r) * 256 + kc + c];
        }
        __syncthreads();
        #pragma unroll 4
        for (int k = 0; k < 64; k++) {
            const float4 a = *(const float4*)&s_A[k][tn * 4];
            const float4 w = *(const float4*)&s_W[k][tm * 4];
            const float av[4] = {a.x, a.y, a.z, a.w};
            const float wv[4] = {w.x, w.y, w.z, w.w};
            #pragma unroll
            for (int i = 0; i < 4; i++)
                #pragma unroll
                for (int j = 0; j < 4; j++)
                    acc[i][j] += av[i] * wv[j];
        }
    }

    #pragma unroll
    for (int i = 0; i < 4; i++) {
        const int n = n0 + tn * 4 + i;
        if (n >= N) continue;
        #pragma unroll
        for (int j = 0; j < 4; j++) {
            const int m = m0 + tm * 4 + j;
            C[n * 256 + m] = lrelu(acc[i][j] + b[m]);
        }
    }
}

// ---------------------------------------------------------------------------
// Pred: out[n] = h[n] . w_pred + b_pred.  One wave per node (4 waves/block).
// ---------------------------------------------------------------------------
__global__ void pred_kernel(const float* __restrict__ h,
                            const float* __restrict__ w,
                            const float* __restrict__ b,
                            float* __restrict__ out, int N)
{
    __shared__ float s_w[256];
    const int t = threadIdx.x;
    s_w[t] = w[t];
    __syncthreads();

    const int wave = t / 64, lane = t % 64;
    const int n = blockIdx.x * 4 + wave;
    if (n >= N) return;

    float v = 0.f;
    #pragma unroll
    for (int j = 0; j < 4; j++)
        v += h[n * 256 + lane + j * 64] * s_w[lane + j * 64];

    #pragma unroll
    for (int off = 32; off > 0; off >>= 1)
        v += __shfl_down(v, off);

    if (lane == 0) out[n] = v + b[0];
}

// ---------------------------------------------------------------------------
extern "C" void kernel_launch(void* const* d_in, const int* in_sizes, int n_in,
                              void* d_out, int out_size, void* d_ws, size_t ws_size,
                              hipStream_t stream)
{
    const float* pose   = (const float*)d_in[0];
    const float* views  = (const float*)d_in[1];
    const int*   ei     = (const int*)d_in[2];
    const float* w_e1   = (const float*)d_in[3];
    const float* b_e1   = (const float*)d_in[4];
    const float* w_e2   = (const float*)d_in[5];
    const float* b_e2   = (const float*)d_in[6];
    const float* w_rel  = (const float*)d_in[7];
    const float* b_rel  = (const float*)d_in[8];
    const float* w_root = (const float*)d_in[9];
    const float* w_l1   = (const float*)d_in[10];
    const float* b_l1   = (const float*)d_in[11];
    const float* w_l2   = (const float*)d_in[12];
    const float* b_l2   = (const float*)d_in[13];
    const float* w_l3   = (const float*)d_in[14];
    const float* b_l3   = (const float*)d_in[15];
    const float* w_pred = (const float*)d_in[16];
    const float* b_pred = (const float*)d_in[17];
    float* out = (float*)d_out;

    const int N = in_sizes[0] / 3;       // 50000
    const int E = in_sizes[2] / 2;       // 4950000

    float* x   = (float*)d_ws;           // N*40
    float* agg = x + (size_t)N * 40;     // N*40
    float* h0  = agg + (size_t)N * 40;   // N*256
    float* h1  = h0 + (size_t)N * 256;   // N*256

    encoder_kernel<<<N, 64, 0, stream>>>(pose, views, w_e1, b_e1, w_e2, b_e2, x);
    hipMemsetAsync(agg, 0, (size_t)N * 40 * sizeof(float), stream);
    scatter_kernel<<<(E + 255) / 256, 256, 0, stream>>>(ei, x, agg, E);

    dim3 gtile((N + 63) / 64, 4);
    graphconv_kernel<<<gtile, 256, 0, stream>>>(agg, x, w_rel, w_root, b_rel, h0, N);
    mlp_kernel<<<gtile, 256, 0, stream>>>(h0, w_l1, b_l1, h1, N);
    mlp_kernel<<<gtile, 256, 0, stream>>>(h1, w_l2, b_l2, h0, N);
    mlp_kernel<<<gtile, 256, 0, stream>>>(h0, w_l3, b_l3, h1, N);
    pred_kernel<<<(N + 3) / 4, 256, 0, stream>>>(h1, w_pred, b_pred, out, N);
}

// Round 2
// 1569.197 us; speedup vs baseline: 6.8943x; 6.8943x over previous
//
#include <hip/hip_runtime.h>

#define NEG_SLOPE 0.1f
__device__ __forceinline__ float lrelu(float v) { return v >= 0.f ? v : NEG_SLOPE * v; }

// ---------------------------------------------------------------------------
// Encoder: per node, conv1d(3->9,k3,s2) + lrelu, conv1d(9->1,k3,s2) + lrelu,
// concat with pose -> x[N][40].  One block (64 threads) per node.
// ---------------------------------------------------------------------------
__global__ void encoder_kernel(const float* __restrict__ pose,
                               const float* __restrict__ views,
                               const float* __restrict__ w1, const float* __restrict__ b1,
                               const float* __restrict__ w2, const float* __restrict__ b2,
                               float* __restrict__ x)
{
    __shared__ float s_in[3 * 151];   // 453
    __shared__ float s_c1[9 * 75];    // 675
    __shared__ float s_w1[81];
    __shared__ float s_b1[9];
    __shared__ float s_w2[27];
    __shared__ float s_b2;

    const int n = blockIdx.x;
    const int t = threadIdx.x;

    for (int i = t; i < 453; i += 64) s_in[i] = views[n * 453 + i];
    for (int i = t; i < 81; i += 64)  s_w1[i] = w1[i];
    if (t < 9)  s_b1[t] = b1[t];
    if (t < 27) s_w2[t] = w2[t];
    if (t == 0) s_b2 = b2[0];
    __syncthreads();

    // conv1: 9 out-channels x 75 positions
    for (int i = t; i < 675; i += 64) {
        const int oc = i / 75, ow = i % 75;
        float v = s_b1[oc];
        #pragma unroll
        for (int ic = 0; ic < 3; ic++) {
            #pragma unroll
            for (int k = 0; k < 3; k++)
                v += s_in[ic * 151 + 2 * ow + k] * s_w1[oc * 9 + ic * 3 + k];
        }
        s_c1[i] = lrelu(v);
    }
    __syncthreads();

    if (t < 3) {
        x[n * 40 + t] = pose[n * 3 + t];
    } else if (t < 40) {
        const int ow = t - 3;
        float v = s_b2;
        #pragma unroll
        for (int ic = 0; ic < 9; ic++) {
            #pragma unroll
            for (int k = 0; k < 3; k++)
                v += s_c1[ic * 75 + 2 * ow + k] * s_w2[ic * 3 + k];
        }
        x[n * 40 + t] = lrelu(v);
    }
}

// ---------------------------------------------------------------------------
// Edge sort by dst (counting sort), replacing 198M fp32 memory-side atomics.
// Phase 1: histogram of dst.
// ---------------------------------------------------------------------------
__global__ void hist_kernel(const int* __restrict__ ei, int* __restrict__ cnt, int E)
{
    const int e = blockIdx.x * blockDim.x + threadIdx.x;
    if (e < E) atomicAdd(&cnt[ei[E + e]], 1);
}

// Phase 2: exclusive scan of counts -> off[0..N], and cursor[i] = off[i].
// Single block, 1024 threads, wave-shuffle scan + wave-carry scan.
// cntcur: input counts, overwritten in-place with exclusive offsets (cursor).
__global__ void scan_kernel(int* cntcur, int* __restrict__ off, int N)
{
    __shared__ int s_wave[16];
    __shared__ int s_carry;
    const int t = threadIdx.x;          // 1024
    const int lane = t & 63, wid = t >> 6;
    if (t == 0) { s_carry = 0; off[0] = 0; }
    __syncthreads();

    for (int base = 0; base < N; base += 1024) {
        const int i = base + t;
        const int v = (i < N) ? cntcur[i] : 0;
        // inclusive scan within wave
        int sc = v;
        #pragma unroll
        for (int d = 1; d < 64; d <<= 1) {
            const int u = __shfl_up(sc, d);
            if (lane >= d) sc += u;
        }
        if (lane == 63) s_wave[wid] = sc;
        __syncthreads();
        if (wid == 0) {
            int wv = (lane < 16) ? s_wave[lane] : 0;
            #pragma unroll
            for (int d = 1; d < 16; d <<= 1) {
                const int u = __shfl_up(wv, d);
                if (lane >= d) wv += u;
            }
            if (lane < 16) s_wave[lane] = wv;   // inclusive over waves
        }
        __syncthreads();
        const int carry = s_carry;
        const int waveoff = (wid > 0) ? s_wave[wid - 1] : 0;
        const int incl = carry + waveoff + sc;
        if (i < N) {
            off[i + 1] = incl;
            cntcur[i] = incl - v;   // exclusive prefix = scatter cursor
        }
        __syncthreads();                         // all reads of s_carry done
        if (t == 0) s_carry = carry + s_wave[15];
        __syncthreads();
    }
}

// Phase 3: scatter src ids into dst-sorted order.
__global__ void sort_scatter_kernel(const int* __restrict__ ei, int* __restrict__ cur,
                                    int* __restrict__ sorted_src, int E)
{
    const int e = blockIdx.x * blockDim.x + threadIdx.x;
    if (e < E) {
        const int d = ei[E + e];
        const int p = atomicAdd(&cur[d], 1);
        sorted_src[p] = ei[e];
    }
}

// Phase 4: atomic-free segment sum. One wave per node; lanes 0..39 own one
// feature each; 4-way unrolled independent row loads for MLP-level ILP.
__global__ void gather_sum_kernel(const int* __restrict__ sorted_src,
                                  const int* __restrict__ off,
                                  const float* __restrict__ x,
                                  float* __restrict__ agg, int N)
{
    const int wave = (blockIdx.x * blockDim.x + threadIdx.x) >> 6;
    const int lane = threadIdx.x & 63;
    if (wave >= N || lane >= 40) return;

    const int s0 = off[wave], s1 = off[wave + 1];
    const float* __restrict__ xl = x + lane;
    float acc = 0.f;
    int e = s0;
    for (; e + 4 <= s1; e += 4) {
        const int i0 = sorted_src[e]     * 40;
        const int i1 = sorted_src[e + 1] * 40;
        const int i2 = sorted_src[e + 2] * 40;
        const int i3 = sorted_src[e + 3] * 40;
        acc += (xl[i0] + xl[i1]) + (xl[i2] + xl[i3]);
    }
    for (; e < s1; e++) acc += xl[sorted_src[e] * 40];
    agg[wave * 40 + lane] = acc;
}

// ---------------------------------------------------------------------------
// GraphConv: h = lrelu([agg|x] @ [w_rel|w_root]^T + b_rel), K=80 GEMM.
// 64x64 tile per 256-thread block, 4x4 per thread.
// ---------------------------------------------------------------------------
__global__ void graphconv_kernel(const float* __restrict__ agg,
                                 const float* __restrict__ x,
                                 const float* __restrict__ w_rel,
                                 const float* __restrict__ w_root,
                                 const float* __restrict__ b_rel,
                                 float* __restrict__ h, int N)
{
    __shared__ float s_A[80][68];
    __shared__ float s_W[80][68];

    const int t = threadIdx.x;
    const int n0 = blockIdx.x * 64;
    const int m0 = blockIdx.y * 64;

    for (int idx = t; idx < 64 * 40; idx += 256) {
        const int r = idx / 40, c = idx % 40;   // node r, k c
        const int n = n0 + r;
        s_A[c][r]      = (n < N) ? agg[n * 40 + c] : 0.f;
        s_A[c + 40][r] = (n < N) ? x[n * 40 + c]   : 0.f;
    }
    for (int idx = t; idx < 64 * 40; idx += 256) {
        const int r = idx / 40, c = idx % 40;   // m r, k c
        s_W[c][r]      = w_rel[(m0 + r) * 40 + c];
        s_W[c + 40][r] = w_root[(m0 + r) * 40 + c];
    }
    __syncthreads();

    const int tm = t % 16, tn = t / 16;
    float acc[4][4] = {};
    for (int k = 0; k < 80; k++) {
        const float4 a = *(const float4*)&s_A[k][tn * 4];
        const float4 w = *(const float4*)&s_W[k][tm * 4];
        const float av[4] = {a.x, a.y, a.z, a.w};
        const float wv[4] = {w.x, w.y, w.z, w.w};
        #pragma unroll
        for (int i = 0; i < 4; i++)
            #pragma unroll
            for (int j = 0; j < 4; j++)
                acc[i][j] += av[i] * wv[j];
    }

    #pragma unroll
    for (int i = 0; i < 4; i++) {
        const int n = n0 + tn * 4 + i;
        if (n >= N) continue;
        #pragma unroll
        for (int j = 0; j < 4; j++) {
            const int m = m0 + tm * 4 + j;
            h[n * 256 + m] = lrelu(acc[i][j] + b_rel[m]);
        }
    }
}

// ---------------------------------------------------------------------------
// MLP layer: C = lrelu(A @ W^T + b), A [N,256], W [256,256] (out-major).
// ---------------------------------------------------------------------------
__global__ void mlp_kernel(const float* __restrict__ A,
                           const float* __restrict__ W,
                           const float* __restrict__ b,
                           float* __restrict__ C, int N)
{
    __shared__ float s_A[64][68];
    __shared__ float s_W[64][68];

    const int t = threadIdx.x;
    const int n0 = blockIdx.x * 64;
    const int m0 = blockIdx.y * 64;
    const int tm = t % 16, tn = t / 16;

    float acc[4][4] = {};
    for (int kc = 0; kc < 256; kc += 64) {
        __syncthreads();
        for (int idx = t; idx < 64 * 64; idx += 256) {
            const int r = idx / 64, c = idx % 64;
            const int n = n0 + r;
            s_A[c][r] = (n < N) ? A[n * 256 + kc + c] : 0.f;
            s_W[c][r] = W[(m0 + r) * 256 + kc + c];
        }
        __syncthreads();
        #pragma unroll 4
        for (int k = 0; k < 64; k++) {
            const float4 a = *(const float4*)&s_A[k][tn * 4];
            const float4 w = *(const float4*)&s_W[k][tm * 4];
            const float av[4] = {a.x, a.y, a.z, a.w};
            const float wv[4] = {w.x, w.y, w.z, w.w};
            #pragma unroll
            for (int i = 0; i < 4; i++)
                #pragma unroll
                for (int j = 0; j < 4; j++)
                    acc[i][j] += av[i] * wv[j];
        }
    }

    #pragma unroll
    for (int i = 0; i < 4; i++) {
        const int n = n0 + tn * 4 + i;
        if (n >= N) continue;
        #pragma unroll
        for (int j = 0; j < 4; j++) {
            const int m = m0 + tm * 4 + j;
            C[n * 256 + m] = lrelu(acc[i][j] + b[m]);
        }
    }
}

// ---------------------------------------------------------------------------
// Pred: out[n] = h[n] . w_pred + b_pred.  One wave per node (4 waves/block).
// ---------------------------------------------------------------------------
__global__ void pred_kernel(const float* __restrict__ h,
                            const float* __restrict__ w,
                            const float* __restrict__ b,
                            float* __restrict__ out, int N)
{
    __shared__ float s_w[256];
    const int t = threadIdx.x;
    s_w[t] = w[t];
    __syncthreads();

    const int wave = t / 64, lane = t % 64;
    const int n = blockIdx.x * 4 + wave;
    if (n >= N) return;

    float v = 0.f;
    #pragma unroll
    for (int j = 0; j < 4; j++)
        v += h[n * 256 + lane + j * 64] * s_w[lane + j * 64];

    #pragma unroll
    for (int off = 32; off > 0; off >>= 1)
        v += __shfl_down(v, off);

    if (lane == 0) out[n] = v + b[0];
}

// ---------------------------------------------------------------------------
extern "C" void kernel_launch(void* const* d_in, const int* in_sizes, int n_in,
                              void* d_out, int out_size, void* d_ws, size_t ws_size,
                              hipStream_t stream)
{
    const float* pose   = (const float*)d_in[0];
    const float* views  = (const float*)d_in[1];
    const int*   ei     = (const int*)d_in[2];
    const float* w_e1   = (const float*)d_in[3];
    const float* b_e1   = (const float*)d_in[4];
    const float* w_e2   = (const float*)d_in[5];
    const float* b_e2   = (const float*)d_in[6];
    const float* w_rel  = (const float*)d_in[7];
    const float* b_rel  = (const float*)d_in[8];
    const float* w_root = (const float*)d_in[9];
    const float* w_l1   = (const float*)d_in[10];
    const float* b_l1   = (const float*)d_in[11];
    const float* w_l2   = (const float*)d_in[12];
    const float* b_l2   = (const float*)d_in[13];
    const float* w_l3   = (const float*)d_in[14];
    const float* b_l3   = (const float*)d_in[15];
    const float* w_pred = (const float*)d_in[16];
    const float* b_pred = (const float*)d_in[17];
    float* out = (float*)d_out;

    const int N = in_sizes[0] / 3;       // 50000
    const int E = in_sizes[2] / 2;       // 4950000

    // Workspace layout (aliasing: sorted_src/off/cur are dead before h0/h1 are
    // first written, and only live after agg's producers are sequenced).
    float* x   = (float*)d_ws;            // N*40 floats
    float* agg = x + (size_t)N * 40;      // N*40 floats
    float* h0  = agg + (size_t)N * 40;    // N*256 floats
    float* h1  = h0 + (size_t)N * 256;    // N*256 floats
    int* sorted_src = (int*)h0;           // E ints   (aliases h0, 19.8MB < 51.2MB)
    int* off        = (int*)h1;           // N+1 ints (aliases h1)
    int* cur        = off + (N + 1);      // N ints   (histogram, then cursor)

    encoder_kernel<<<N, 64, 0, stream>>>(pose, views, w_e1, b_e1, w_e2, b_e2, x);

    // --- counting sort of edges by dst, then atomic-free segment sum ---
    hipMemsetAsync(cur, 0, (size_t)N * sizeof(int), stream);
    hist_kernel<<<(E + 255) / 256, 256, 0, stream>>>(ei, cur, E);
    scan_kernel<<<1, 1024, 0, stream>>>(cur, off, N);
    sort_scatter_kernel<<<(E + 255) / 256, 256, 0, stream>>>(ei, cur, sorted_src, E);
    gather_sum_kernel<<<(N + 3) / 4, 256, 0, stream>>>(sorted_src, off, x, agg, N);

    dim3 gtile((N + 63) / 64, 4);
    graphconv_kernel<<<gtile, 256, 0, stream>>>(agg, x, w_rel, w_root, b_rel, h0, N);
    mlp_kernel<<<gtile, 256, 0, stream>>>(h0, w_l1, b_l1, h1, N);
    mlp_kernel<<<gtile, 256, 0, stream>>>(h1, w_l2, b_l2, h0, N);
    mlp_kernel<<<gtile, 256, 0, stream>>>(h0, w_l3, b_l3, h1, N);
    pred_kernel<<<(N + 3) / 4, 256, 0, stream>>>(h1, w_pred, b_pred, out, N);
}